// Round 23
// baseline (184.250 us; speedup 1.0000x reference)
//
#include <hip/hip_runtime.h>
#include <math.h>

typedef float  f32x4  __attribute__((ext_vector_type(4)));
typedef int    i32x4  __attribute__((ext_vector_type(4)));
typedef double f64x4  __attribute__((ext_vector_type(4)));

#define H      4096
#define E      64
#define TOPK   8
#define TILE_T 16
#define CK     256     // k per staged chunk
#define MS     4       // 64-k MFMA steps per chunk
#define NCH    8       // chunks per block (K-half)

#define WB_OFF   0
#define COMP_OFF 1310720
#define LG_OFF   2097152   // f64 logits [16384][64] = 8 MB

// W -> 5 balanced i8 limbs of round(w*2^41), B-fragment order for 16x16x64
// (R11-proven): Wb[((m*4+eq)*5+j)*1024 + lane*16 + slot], lane=(kgrp<<4)|(e&15)
__global__ __launch_bounds__(256)
void prep_w(const float* __restrict__ Wg, signed char* __restrict__ Wb)
{
  int n = blockIdx.x * 256 + threadIdx.x;   // 16384 = e(64) x m(64) x kgrp(4)
  int kgrp = n & 3, m = (n >> 2) & 63, e = n >> 8;
  const float* wp = Wg + e * 4096 + m * 64 + kgrp * 16;
  signed char lb[5][16];
  #pragma unroll
  for (int s = 0; s < 16; ++s) {
    long long v = (long long)rint((double)wp[s] * 2199023255552.0); // 2^41
    #pragma unroll
    for (int j = 0; j < 4; ++j) {
      signed char b = (signed char)(v & 0xff);
      lb[j][s] = b;
      v = (v - b) >> 8;
    }
    lb[4][s] = (signed char)v;
  }
  int lanei = (kgrp << 4) | (e & 15);
  int eq = e >> 4;
  #pragma unroll
  for (int j = 0; j < 5; ++j) {
    i32x4 d;
    #pragma unroll
    for (int r = 0; r < 4; ++r)
      d[r] = (lb[j][4*r] & 0xFF) | ((lb[j][4*r+1] & 0xFF) << 8)
           | ((lb[j][4*r+2] & 0xFF) << 16) | ((lb[j][4*r+3] & 0xFF) << 24);
    *(i32x4*)(Wb + (((size_t)(m * 4 + eq) * 5 + j) << 10) + lanei * 16) = d;
  }
}

// comp[kH][e] = C0 * sum_{k in K-half} round(w*2^41) (R9-proven 2-way form).
__global__ __launch_bounds__(64)
void comp_w(const float* __restrict__ Wg, double* __restrict__ compT)
{
  int b = blockIdx.x;            // 128 = kH(2) x e(64)
  int kH = b >> 6, e = b & 63;
  int lane = threadIdx.x;
  double s = 0.0;
  #pragma unroll 4
  for (int i = 0; i < 32; ++i)
    s += rint((double)Wg[e * 4096 + kH * 2048 + i * 64 + lane] * 2199023255552.0);
  #pragma unroll
  for (int off = 32; off >= 1; off >>= 1)
    s += __shfl_xor(s, off);
  if (lane == 0) compT[kH * 64 + e] = 8421504.0 * s;
}

// zero the f64 logits accumulator (1M doubles)
__global__ __launch_bounds__(256)
void zero_lg(double* __restrict__ lg)
{
  size_t i = ((size_t)blockIdx.x * 256 + threadIdx.x) * 4;
  f64x4 z4 = {0.0, 0.0, 0.0, 0.0};
  *(f64x4*)(lg + i) = z4;
}

// R23 = R20's proven inner loop (coalesced stage + single CONV + 2-way-free
// scatter + consume) with K SPLIT IN HALVES across blocks: grid 2048 ->
// 8 blocks/CU (R20 was grid-capped at 4). Tests occupancy scaling WITHOUT
// R19's TA-bound staging confound. f64 partials (+per-half comp) combined
// via unsafeAtomicAdd (2 adds/cell, commutative -> bit-exact, order-free).
__global__ __launch_bounds__(256)
void moe_part(const float* __restrict__ X, const signed char* __restrict__ Wb,
              const double* __restrict__ compT, double* __restrict__ lg)
{
  __shared__ char As[16384];     // [kgrp16][limb4][tok16]x16B, swizzled

  const int bid  = blockIdx.x;
  const int tile = bid >> 1;
  const int kH   = bid & 1;
  const int t0   = tile * TILE_T;

  const int tid  = threadIdx.x;
  const int lane = tid & 63;
  const int w    = tid >> 6;     // expert quad 0..3 (also stager of 4 rows)
  const int l15  = lane & 15;
  const int kg   = lane >> 4;

  // ---- probe (lane,reg)->(row,col) readout (R11-proven) ----
  i32x4 z = {0, 0, 0, 0};
  int lab = l15 * 0x01010101;
  i32x4 onev = {0x01010101, 0x01010101, 0x01010101, 0x01010101};
  i32x4 labv = {lab, lab, lab, lab};
  i32x4 pr = __builtin_amdgcn_mfma_i32_16x16x64_i8(labv, onev, z, 0, 0, 0);
  i32x4 pc = __builtin_amdgcn_mfma_i32_16x16x64_i8(onev, labv, z, 0, 0, 0);
  int qrow[4], qcol[4];
  #pragma unroll
  for (int r = 0; r < 4; ++r) { qrow[r] = pr[r] >> 6; qcol[r] = pc[r] >> 6; }

  i32x4 acc3 = z, acc4 = z, acc5 = z, acc6 = z, acc7 = z;

  // staging (R20-proven): wave w stages rows w*4..w*4+3, one coalesced
  // f32x4 per row; per-lane CONV; b32 scatter at 2 lanes/bank (free)
  const int kgrp = lane >> 2;                  // 0..15
  const int wrd  = lane & 3;
  const int swzs = ((lane >> 3) & 7) << 4;     // ((kgrp>>1)&7)<<4
  const float* xbase = X + (size_t)t0 * H + kH * 2048 + lane * 4;

  // B: global k64-step m = kH*32 + local -> base (kH*128 + w)*5120
  const signed char* bpp = Wb + (size_t)(kH * 128 + w) * 5120 + lane * 16;

  for (int c = 0; c < NCH; ++c) {
    // ---- coalesced load: one f32x4 per row (4 rows per wave) ----
    f32x4 xr[4];
    #pragma unroll
    for (int q = 0; q < 4; ++q)
      xr[q] = *(const f32x4*)(xbase + (size_t)(w * 4 + q) * H + c * CK);

    // ---- per-lane CONV (once) + swizzled b32 scatter (R20-proven) ----
    #pragma unroll
    for (int q = 0; q < 4; ++q) {
      const int r = w * 4 + q;
      unsigned u0 = ((unsigned)(int)(xr[q][0] * 268435456.0f)) ^ 0x00808080u;
      unsigned u1 = ((unsigned)(int)(xr[q][1] * 268435456.0f)) ^ 0x00808080u;
      unsigned u2 = ((unsigned)(int)(xr[q][2] * 268435456.0f)) ^ 0x00808080u;
      unsigned u3 = ((unsigned)(int)(xr[q][3] * 268435456.0f)) ^ 0x00808080u;
      unsigned p01, p23, W0, W1, W2, W3;
      p01 = __builtin_amdgcn_perm(u1, u0, 0x04000400u);
      p23 = __builtin_amdgcn_perm(u3, u2, 0x04000400u);
      W0  = __builtin_amdgcn_perm(p23, p01, 0x05040100u);
      p01 = __builtin_amdgcn_perm(u1, u0, 0x05010501u);
      p23 = __builtin_amdgcn_perm(u3, u2, 0x05010501u);
      W1  = __builtin_amdgcn_perm(p23, p01, 0x05040100u);
      p01 = __builtin_amdgcn_perm(u1, u0, 0x06020602u);
      p23 = __builtin_amdgcn_perm(u3, u2, 0x06020602u);
      W2  = __builtin_amdgcn_perm(p23, p01, 0x05040100u);
      p01 = __builtin_amdgcn_perm(u1, u0, 0x07030703u);
      p23 = __builtin_amdgcn_perm(u3, u2, 0x07030703u);
      W3  = __builtin_amdgcn_perm(p23, p01, 0x05040100u);
      char* base = As + (kgrp << 10) + (((r << 4) ^ swzs)) + (wrd << 2);
      *(unsigned*)(base + 0x000) = W0;
      *(unsigned*)(base + 0x100) = W1;
      *(unsigned*)(base + 0x200) = W2;
      *(unsigned*)(base + 0x300) = W3;
    }
    __syncthreads();

    // ---- consume: MS steps x {4 ds_read + 5 B loads + 14 MFMAs} ----
    #pragma unroll
    for (int m = 0; m < MS; ++m) {
      const int kq   = 4 * m + kg;
      const int swzr = ((kq >> 1) & 7) << 4;
      const char* abase = As + (kq << 10) + (((l15 << 4) ^ swzr));
      i32x4 a0 = *(const i32x4*)(abase + 0x000);
      i32x4 a1 = *(const i32x4*)(abase + 0x100);
      i32x4 a2 = *(const i32x4*)(abase + 0x200);
      i32x4 a3 = *(const i32x4*)(abase + 0x300);
      i32x4 b0 = *(const i32x4*)(bpp);
      i32x4 b1 = *(const i32x4*)(bpp + 1024);
      i32x4 b2 = *(const i32x4*)(bpp + 2048);
      i32x4 b3 = *(const i32x4*)(bpp + 3072);
      i32x4 b4 = *(const i32x4*)(bpp + 4096);
      bpp += 20480;
      acc3 = __builtin_amdgcn_mfma_i32_16x16x64_i8(a0, b3, acc3, 0, 0, 0);
      acc4 = __builtin_amdgcn_mfma_i32_16x16x64_i8(a0, b4, acc4, 0, 0, 0);
      acc5 = __builtin_amdgcn_mfma_i32_16x16x64_i8(a1, b4, acc5, 0, 0, 0);
      acc6 = __builtin_amdgcn_mfma_i32_16x16x64_i8(a2, b4, acc6, 0, 0, 0);
      acc7 = __builtin_amdgcn_mfma_i32_16x16x64_i8(a3, b4, acc7, 0, 0, 0);
      acc3 = __builtin_amdgcn_mfma_i32_16x16x64_i8(a1, b2, acc3, 0, 0, 0);
      acc4 = __builtin_amdgcn_mfma_i32_16x16x64_i8(a1, b3, acc4, 0, 0, 0);
      acc5 = __builtin_amdgcn_mfma_i32_16x16x64_i8(a2, b3, acc5, 0, 0, 0);
      acc6 = __builtin_amdgcn_mfma_i32_16x16x64_i8(a3, b3, acc6, 0, 0, 0);
      acc3 = __builtin_amdgcn_mfma_i32_16x16x64_i8(a2, b1, acc3, 0, 0, 0);
      acc4 = __builtin_amdgcn_mfma_i32_16x16x64_i8(a2, b2, acc4, 0, 0, 0);
      acc5 = __builtin_amdgcn_mfma_i32_16x16x64_i8(a3, b2, acc5, 0, 0, 0);
      acc3 = __builtin_amdgcn_mfma_i32_16x16x64_i8(a3, b0, acc3, 0, 0, 0);
      acc4 = __builtin_amdgcn_mfma_i32_16x16x64_i8(a3, b1, acc4, 0, 0, 0);
    }
    __syncthreads();
  }

  // ---- f64 partial + per-half comp -> atomic accumulate (order-free) ----
  #pragma unroll
  for (int r = 0; r < 4; ++r) {
    int ex = w * 16 + qcol[r];
    double part = (16777216.0              * (double)acc3[r]
                 + 4294967296.0            * (double)acc4[r]
                 + 1099511627776.0         * (double)acc5[r]
                 + 281474976710656.0       * (double)acc6[r]
                 + 72057594037927936.0     * (double)acc7[r]
                 + compT[kH * 64 + ex]) * 1.6940658945086007e-21;
    unsafeAtomicAdd(&lg[(size_t)(t0 + qrow[r]) * E + ex], part);
  }
}

// finish: softmax + top-8 from f64 logits (R19-proven).
__global__ __launch_bounds__(256)
void moe_fin(const double* __restrict__ lg, float* __restrict__ out,
             int n_tokens)
{
  const int tid  = threadIdx.x;
  const int lane = tid & 63;
  const int wv   = tid >> 6;

  for (int i = 0; i < 16; ++i) {
    int t = blockIdx.x * 64 + wv * 16 + i;
    double val = lg[(size_t)t * E + lane];

    double mx = val;
    #pragma unroll
    for (int off = 32; off >= 1; off >>= 1)
      mx = fmax(mx, __shfl_xor(mx, off));

    float p = expf((float)(val - mx));
    float S = p;
    #pragma unroll
    for (int off = 32; off >= 1; off >>= 1)
      S += __shfl_xor(S, off);

    double cur = val;
    float myw = 0.f; int myidx = 0;
    float psum = 0.f;
    #pragma unroll
    for (int r = 0; r < TOPK; r++) {
      double v = cur; int ii = lane;
      #pragma unroll
      for (int off = 32; off >= 1; off >>= 1) {
        double ov = __shfl_xor(v, off);
        int    oi = __shfl_xor(ii, off);
        if (ov > v || (ov == v && oi < ii)) { v = ov; ii = oi; }
      }
      float pw = __shfl(p, ii);
      psum += pw;
      if (lane == r) { myw = pw; myidx = ii; }
      if (lane == ii) cur = -INFINITY;
    }
    float denom = psum + 1e-20f * S;
    if (lane < TOPK) {
      size_t gt = (size_t)t;
      out[gt * TOPK + lane] = myw / denom;
      out[(size_t)n_tokens * TOPK + gt * TOPK + lane] = (float)myidx;
    }
  }
}

extern "C" void kernel_launch(void* const* d_in, const int* in_sizes, int n_in,
                              void* d_out, int out_size, void* d_ws, size_t ws_size,
                              hipStream_t stream)
{
  const float* X  = (const float*)d_in[0];
  const float* Wg = (const float*)d_in[1];
  float* out = (float*)d_out;
  signed char* Wb = (signed char*)((char*)d_ws + WB_OFF);   // 1.25 MB
  double* compT   = (double*)((char*)d_ws + COMP_OFF);      // 1 KB
  double* lg      = (double*)((char*)d_ws + LG_OFF);        // 8 MB
  int n_tokens = in_sizes[0] / H;                            // 16384

  prep_w<<<64, 256, 0, stream>>>(Wg, Wb);
  comp_w<<<128, 64, 0, stream>>>(Wg, compT);
  zero_lg<<<1024, 256, 0, stream>>>(lg);
  moe_part<<<(n_tokens / TILE_T) * 2, 256, 0, stream>>>(X, Wb, compT, lg);
  moe_fin<<<n_tokens / 64, 256, 0, stream>>>(lg, out, n_tokens);
}

// Round 24
// 121.545 us; speedup vs baseline: 1.5159x; 1.5159x over previous
//
#include <hip/hip_runtime.h>
#include <math.h>

typedef float  f32x4  __attribute__((ext_vector_type(4)));
typedef int    i32x4  __attribute__((ext_vector_type(4)));

#define H      4096
#define E      64
#define TOPK   8
#define TILE_T 16
#define CK     512     // k per staged chunk (R24: 256 -> 512, halves barriers)
#define MS     8       // 64-k MFMA steps per chunk
#define NCH    8       // chunks

// W -> 5 balanced i8 limbs of round(w*2^41), B-fragment order for 16x16x64
// (R11-proven): Wb[((m*4+eq)*5+j)*1024 + lane*16 + slot], lane=(kgrp<<4)|(e&15)
__global__ __launch_bounds__(256)
void prep_w(const float* __restrict__ Wg, signed char* __restrict__ Wb)
{
  int n = blockIdx.x * 256 + threadIdx.x;   // 16384 = e(64) x m(64) x kgrp(4)
  int kgrp = n & 3, m = (n >> 2) & 63, e = n >> 8;
  const float* wp = Wg + e * 4096 + m * 64 + kgrp * 16;
  signed char lb[5][16];
  #pragma unroll
  for (int s = 0; s < 16; ++s) {
    long long v = (long long)rint((double)wp[s] * 2199023255552.0); // 2^41
    #pragma unroll
    for (int j = 0; j < 4; ++j) {
      signed char b = (signed char)(v & 0xff);
      lb[j][s] = b;
      v = (v - b) >> 8;
    }
    lb[4][s] = (signed char)v;
  }
  int lanei = (kgrp << 4) | (e & 15);
  int eq = e >> 4;
  #pragma unroll
  for (int j = 0; j < 5; ++j) {
    i32x4 d;
    #pragma unroll
    for (int r = 0; r < 4; ++r)
      d[r] = (lb[j][4*r] & 0xFF) | ((lb[j][4*r+1] & 0xFF) << 8)
           | ((lb[j][4*r+2] & 0xFF) << 16) | ((lb[j][4*r+3] & 0xFF) << 24);
    *(i32x4*)(Wb + (((size_t)(m * 4 + eq) * 5 + j) << 10) + lanei * 16) = d;
  }
}

// comp[e] = C0 * sum_k round(w*2^41), full K (R11-proven).
__global__ __launch_bounds__(64)
void comp_w(const float* __restrict__ Wg, double* __restrict__ compT)
{
  int e = blockIdx.x;
  int lane = threadIdx.x;
  double s = 0.0;
  #pragma unroll 4
  for (int i = 0; i < 64; ++i)
    s += rint((double)Wg[e * 4096 + i * 64 + lane] * 2199023255552.0);
  #pragma unroll
  for (int off = 32; off >= 1; off >>= 1)
    s += __shfl_xor(s, off);
  if (lane == 0) compT[e] = 8421504.0 * s;
}

// R24 = R20 (best: 118.8us wall) with CK=512: 8 chunks instead of 16 ->
// half the barrier/drain events, 112-MFMA runs between barriers. Staging
// map, single CONV, 2-way-free scatter, swizzle, numerics all R20-proven.
// As = 32KB single-buffer -> still 4 blocks/CU at grid 1024.
__global__ __launch_bounds__(256)
void moe_gate_i8(const float* __restrict__ X, const signed char* __restrict__ Wb,
                 const double* __restrict__ compT, float* __restrict__ out,
                 int n_tokens)
{
  __shared__ char As[32768];     // [kgrp32][limb4][tok16]x16B, swizzled
  double* Ls = (double*)As;      // aliased epilogue logits [16][64]

  const int tid  = threadIdx.x;
  const int lane = tid & 63;
  const int w    = tid >> 6;     // expert quad 0..3 (also stager of 4 rows)
  const int t0   = blockIdx.x * TILE_T;
  const int l15  = lane & 15;
  const int kg   = lane >> 4;

  // ---- probe (lane,reg)->(row,col) readout (R11-proven) ----
  i32x4 z = {0, 0, 0, 0};
  int lab = l15 * 0x01010101;
  i32x4 onev = {0x01010101, 0x01010101, 0x01010101, 0x01010101};
  i32x4 labv = {lab, lab, lab, lab};
  i32x4 pr = __builtin_amdgcn_mfma_i32_16x16x64_i8(labv, onev, z, 0, 0, 0);
  i32x4 pc = __builtin_amdgcn_mfma_i32_16x16x64_i8(onev, labv, z, 0, 0, 0);
  int qrow[4], qcol[4];
  #pragma unroll
  for (int r = 0; r < 4; ++r) { qrow[r] = pr[r] >> 6; qcol[r] = pc[r] >> 6; }

  i32x4 acc3 = z, acc4 = z, acc5 = z, acc6 = z, acc7 = z;

  // staging (R20-proven): wave w stages rows w*4..w*4+3; per chunk each row
  // is 512 floats = 2 coalesced f32x4 per lane (halves hf=0/1)
  const int kgrp0 = lane >> 2;                 // 0..15 (hf=0); +16 for hf=1
  const int wrd   = lane & 3;
  const float* xbase = X + (size_t)t0 * H + lane * 4;

  const signed char* bpp = Wb + w * 5120 + lane * 16;

  for (int c = 0; c < NCH; ++c) {
    // ---- coalesced load: 2 f32x4 per row (4 rows per wave) ----
    f32x4 xr[8];
    #pragma unroll
    for (int q = 0; q < 4; ++q) {
      xr[q]     = *(const f32x4*)(xbase + (size_t)(w * 4 + q) * H + c * CK);
      xr[4 + q] = *(const f32x4*)(xbase + (size_t)(w * 4 + q) * H + c * CK + 256);
    }

    // ---- per-lane CONV (once) + swizzled b32 scatter (R20-proven) ----
    #pragma unroll
    for (int hf = 0; hf < 2; ++hf) {
      const int kgrp = kgrp0 + hf * 16;
      const int swzs = ((kgrp >> 1) & 7) << 4;
      #pragma unroll
      for (int q = 0; q < 4; ++q) {
        const int r = w * 4 + q;
        f32x4 xv = xr[hf * 4 + q];
        unsigned u0 = ((unsigned)(int)(xv[0] * 268435456.0f)) ^ 0x00808080u;
        unsigned u1 = ((unsigned)(int)(xv[1] * 268435456.0f)) ^ 0x00808080u;
        unsigned u2 = ((unsigned)(int)(xv[2] * 268435456.0f)) ^ 0x00808080u;
        unsigned u3 = ((unsigned)(int)(xv[3] * 268435456.0f)) ^ 0x00808080u;
        unsigned p01, p23, W0, W1, W2, W3;
        p01 = __builtin_amdgcn_perm(u1, u0, 0x04000400u);
        p23 = __builtin_amdgcn_perm(u3, u2, 0x04000400u);
        W0  = __builtin_amdgcn_perm(p23, p01, 0x05040100u);
        p01 = __builtin_amdgcn_perm(u1, u0, 0x05010501u);
        p23 = __builtin_amdgcn_perm(u3, u2, 0x05010501u);
        W1  = __builtin_amdgcn_perm(p23, p01, 0x05040100u);
        p01 = __builtin_amdgcn_perm(u1, u0, 0x06020602u);
        p23 = __builtin_amdgcn_perm(u3, u2, 0x06020602u);
        W2  = __builtin_amdgcn_perm(p23, p01, 0x05040100u);
        p01 = __builtin_amdgcn_perm(u1, u0, 0x07030703u);
        p23 = __builtin_amdgcn_perm(u3, u2, 0x07030703u);
        W3  = __builtin_amdgcn_perm(p23, p01, 0x05040100u);
        char* base = As + (kgrp << 10) + (((r << 4) ^ swzs)) + (wrd << 2);
        *(unsigned*)(base + 0x000) = W0;
        *(unsigned*)(base + 0x100) = W1;
        *(unsigned*)(base + 0x200) = W2;
        *(unsigned*)(base + 0x300) = W3;
      }
    }
    __syncthreads();

    // ---- consume: MS=8 steps x {4 ds_read + 5 B loads + 14 MFMAs} ----
    #pragma unroll
    for (int m = 0; m < MS; ++m) {
      const int kq   = 4 * m + kg;             // 0..31
      const int swzr = ((kq >> 1) & 7) << 4;
      const char* abase = As + (kq << 10) + (((l15 << 4) ^ swzr));
      i32x4 a0 = *(const i32x4*)(abase + 0x000);
      i32x4 a1 = *(const i32x4*)(abase + 0x100);
      i32x4 a2 = *(const i32x4*)(abase + 0x200);
      i32x4 a3 = *(const i32x4*)(abase + 0x300);
      i32x4 b0 = *(const i32x4*)(bpp);
      i32x4 b1 = *(const i32x4*)(bpp + 1024);
      i32x4 b2 = *(const i32x4*)(bpp + 2048);
      i32x4 b3 = *(const i32x4*)(bpp + 3072);
      i32x4 b4 = *(const i32x4*)(bpp + 4096);
      bpp += 20480;
      acc3 = __builtin_amdgcn_mfma_i32_16x16x64_i8(a0, b3, acc3, 0, 0, 0);
      acc4 = __builtin_amdgcn_mfma_i32_16x16x64_i8(a0, b4, acc4, 0, 0, 0);
      acc5 = __builtin_amdgcn_mfma_i32_16x16x64_i8(a1, b4, acc5, 0, 0, 0);
      acc6 = __builtin_amdgcn_mfma_i32_16x16x64_i8(a2, b4, acc6, 0, 0, 0);
      acc7 = __builtin_amdgcn_mfma_i32_16x16x64_i8(a3, b4, acc7, 0, 0, 0);
      acc3 = __builtin_amdgcn_mfma_i32_16x16x64_i8(a1, b2, acc3, 0, 0, 0);
      acc4 = __builtin_amdgcn_mfma_i32_16x16x64_i8(a1, b3, acc4, 0, 0, 0);
      acc5 = __builtin_amdgcn_mfma_i32_16x16x64_i8(a2, b3, acc5, 0, 0, 0);
      acc6 = __builtin_amdgcn_mfma_i32_16x16x64_i8(a3, b3, acc6, 0, 0, 0);
      acc3 = __builtin_amdgcn_mfma_i32_16x16x64_i8(a2, b1, acc3, 0, 0, 0);
      acc4 = __builtin_amdgcn_mfma_i32_16x16x64_i8(a2, b2, acc4, 0, 0, 0);
      acc5 = __builtin_amdgcn_mfma_i32_16x16x64_i8(a3, b2, acc5, 0, 0, 0);
      acc3 = __builtin_amdgcn_mfma_i32_16x16x64_i8(a3, b0, acc3, 0, 0, 0);
      acc4 = __builtin_amdgcn_mfma_i32_16x16x64_i8(a3, b1, acc4, 0, 0, 0);
    }
    __syncthreads();
  }

  // ---- f64 combine: wave owns its 16x16 logits (R11-proven) ----
  #pragma unroll
  for (int r = 0; r < 4; ++r) {
    int ex = w * 16 + qcol[r];
    double part = (16777216.0              * (double)acc3[r]
                 + 4294967296.0            * (double)acc4[r]
                 + 1099511627776.0         * (double)acc5[r]
                 + 281474976710656.0       * (double)acc6[r]
                 + 72057594037927936.0     * (double)acc7[r]
                 + compT[ex]) * 1.6940658945086007e-21;
    Ls[qrow[r] * E + ex] = part;
  }
  __syncthreads();

  // ---- softmax + top-8: selection on f64 logits, weights in f32 ----
  for (int tt2 = 0; tt2 < 4; tt2++) {
    int t = w * 4 + tt2;
    double val = Ls[t * E + lane];

    double mx = val;
    #pragma unroll
    for (int off = 32; off >= 1; off >>= 1)
      mx = fmax(mx, __shfl_xor(mx, off));

    float p = expf((float)(val - mx));
    float S = p;
    #pragma unroll
    for (int off = 32; off >= 1; off >>= 1)
      S += __shfl_xor(S, off);

    double cur = val;
    float myw = 0.f; int myidx = 0;
    float psum = 0.f;
    #pragma unroll
    for (int r = 0; r < TOPK; r++) {
      double v = cur; int ii = lane;
      #pragma unroll
      for (int off = 32; off >= 1; off >>= 1) {
        double ov = __shfl_xor(v, off);
        int    oi = __shfl_xor(ii, off);
        if (ov > v || (ov == v && oi < ii)) { v = ov; ii = oi; }
      }
      float pw = __shfl(p, ii);
      psum += pw;
      if (lane == r) { myw = pw; myidx = ii; }
      if (lane == ii) cur = -INFINITY;
    }
    float denom = psum + 1e-20f * S;
    if (lane < TOPK) {
      size_t gt = (size_t)(t0 + t);
      out[gt * TOPK + lane] = myw / denom;
      out[(size_t)n_tokens * TOPK + gt * TOPK + lane] = (float)myidx;
    }
  }
}

extern "C" void kernel_launch(void* const* d_in, const int* in_sizes, int n_in,
                              void* d_out, int out_size, void* d_ws, size_t ws_size,
                              hipStream_t stream)
{
  const float* X  = (const float*)d_in[0];
  const float* Wg = (const float*)d_in[1];
  float* out = (float*)d_out;
  signed char* Wb = (signed char*)d_ws;                 // 1.25 MB limb planes
  double* compT   = (double*)((char*)d_ws + 1310720);   // 512 B comp table
  int n_tokens = in_sizes[0] / H;                        // 16384

  prep_w<<<64, 256, 0, stream>>>(Wg, Wb);
  comp_w<<<64, 64, 0, stream>>>(Wg, compT);
  moe_gate_i8<<<n_tokens / TILE_T, 256, 0, stream>>>(X, Wb, compT, out, n_tokens);
}

// Round 25
// 121.450 us; speedup vs baseline: 1.5171x; 1.0008x over previous
//
#include <hip/hip_runtime.h>
#include <math.h>

typedef float  f32x4  __attribute__((ext_vector_type(4)));
typedef int    i32x4  __attribute__((ext_vector_type(4)));

#define H      4096
#define E      64
#define TOPK   8
#define TILE_T 16
#define CK     256     // k per staged chunk
#define MS     4       // 64-k MFMA steps per chunk
#define NCH    16      // chunks

// W -> 5 balanced i8 limbs of round(w*2^41) (R11-proven layout) + FUSED comp
// accumulation: thread's 16 rint values summed (exact ints <= 2^42 in f64),
// wave-reduced (same e per wave), one f64 atomicAdd per wave -> compRaw[e].
// Order-free & bit-exact (integer adds). R25: removes the 4096-thread comp_w
// launch-tail (~10-20us at 16 threads/CU).
__global__ __launch_bounds__(256)
void prep_w(const float* __restrict__ Wg, signed char* __restrict__ Wb,
            double* __restrict__ compRaw)
{
  int n = blockIdx.x * 256 + threadIdx.x;   // 16384 = e(64) x m(64) x kgrp(4)
  int kgrp = n & 3, m = (n >> 2) & 63, e = n >> 8;
  const float* wp = Wg + e * 4096 + m * 64 + kgrp * 16;
  signed char lb[5][16];
  double csum = 0.0;
  #pragma unroll
  for (int s = 0; s < 16; ++s) {
    long long v = (long long)rint((double)wp[s] * 2199023255552.0); // 2^41
    csum += (double)v;
    #pragma unroll
    for (int j = 0; j < 4; ++j) {
      signed char b = (signed char)(v & 0xff);
      lb[j][s] = b;
      v = (v - b) >> 8;
    }
    lb[4][s] = (signed char)v;
  }
  int lanei = (kgrp << 4) | (e & 15);
  int eq = e >> 4;
  #pragma unroll
  for (int j = 0; j < 5; ++j) {
    i32x4 d;
    #pragma unroll
    for (int r = 0; r < 4; ++r)
      d[r] = (lb[j][4*r] & 0xFF) | ((lb[j][4*r+1] & 0xFF) << 8)
           | ((lb[j][4*r+2] & 0xFF) << 16) | ((lb[j][4*r+3] & 0xFF) << 24);
    *(i32x4*)(Wb + (((size_t)(m * 4 + eq) * 5 + j) << 10) + lanei * 16) = d;
  }
  // wave covers 64 consecutive n = same e (n = e*256 + ...): exact reduce
  #pragma unroll
  for (int off = 32; off >= 1; off >>= 1)
    csum += __shfl_xor(csum, off);
  if ((threadIdx.x & 63) == 0)
    unsafeAtomicAdd(&compRaw[e], csum);     // integer-valued: order-free exact
}

// R25 main = R20 VERBATIM (best: 118.8us wall; 9 structural variants all
// regressed/nulled against it), except compT -> 8421504.0*compRaw at use
// (same single f64 rounding as the precomputed form, ~1e-17 logit effect).
__global__ __launch_bounds__(256)
void moe_gate_i8(const float* __restrict__ X, const signed char* __restrict__ Wb,
                 const double* __restrict__ compRaw, float* __restrict__ out,
                 int n_tokens)
{
  __shared__ char As[16384];     // [kgrp16][limb4][tok16]x16B, swizzled
  double* Ls = (double*)As;      // aliased epilogue logits [16][64]

  const int tid  = threadIdx.x;
  const int lane = tid & 63;
  const int w    = tid >> 6;     // expert quad 0..3 (also stager of 4 rows)
  const int t0   = blockIdx.x * TILE_T;
  const int l15  = lane & 15;
  const int kg   = lane >> 4;

  // ---- probe (lane,reg)->(row,col) readout (R11-proven) ----
  i32x4 z = {0, 0, 0, 0};
  int lab = l15 * 0x01010101;
  i32x4 onev = {0x01010101, 0x01010101, 0x01010101, 0x01010101};
  i32x4 labv = {lab, lab, lab, lab};
  i32x4 pr = __builtin_amdgcn_mfma_i32_16x16x64_i8(labv, onev, z, 0, 0, 0);
  i32x4 pc = __builtin_amdgcn_mfma_i32_16x16x64_i8(onev, labv, z, 0, 0, 0);
  int qrow[4], qcol[4];
  #pragma unroll
  for (int r = 0; r < 4; ++r) { qrow[r] = pr[r] >> 6; qcol[r] = pc[r] >> 6; }

  i32x4 acc3 = z, acc4 = z, acc5 = z, acc6 = z, acc7 = z;

  // staging (R20-proven): wave w stages rows w*4..w*4+3, one coalesced
  // f32x4 per row; per-lane CONV; b32 scatter at 2 lanes/bank (free)
  const int kgrp = lane >> 2;                  // 0..15
  const int wrd  = lane & 3;
  const int swzs = ((lane >> 3) & 7) << 4;     // ((kgrp>>1)&7)<<4
  const float* xbase = X + (size_t)t0 * H + lane * 4;

  const signed char* bpp = Wb + w * 5120 + lane * 16;

  for (int c = 0; c < NCH; ++c) {
    // ---- coalesced load: one f32x4 per row (4 rows per wave) ----
    f32x4 xr[4];
    #pragma unroll
    for (int q = 0; q < 4; ++q)
      xr[q] = *(const f32x4*)(xbase + (size_t)(w * 4 + q) * H + c * CK);

    // ---- per-lane CONV (once per block) + swizzled b32 scatter ----
    #pragma unroll
    for (int q = 0; q < 4; ++q) {
      const int r = w * 4 + q;
      unsigned u0 = ((unsigned)(int)(xr[q][0] * 268435456.0f)) ^ 0x00808080u;
      unsigned u1 = ((unsigned)(int)(xr[q][1] * 268435456.0f)) ^ 0x00808080u;
      unsigned u2 = ((unsigned)(int)(xr[q][2] * 268435456.0f)) ^ 0x00808080u;
      unsigned u3 = ((unsigned)(int)(xr[q][3] * 268435456.0f)) ^ 0x00808080u;
      unsigned p01, p23, W0, W1, W2, W3;
      p01 = __builtin_amdgcn_perm(u1, u0, 0x04000400u);
      p23 = __builtin_amdgcn_perm(u3, u2, 0x04000400u);
      W0  = __builtin_amdgcn_perm(p23, p01, 0x05040100u);
      p01 = __builtin_amdgcn_perm(u1, u0, 0x05010501u);
      p23 = __builtin_amdgcn_perm(u3, u2, 0x05010501u);
      W1  = __builtin_amdgcn_perm(p23, p01, 0x05040100u);
      p01 = __builtin_amdgcn_perm(u1, u0, 0x06020602u);
      p23 = __builtin_amdgcn_perm(u3, u2, 0x06020602u);
      W2  = __builtin_amdgcn_perm(p23, p01, 0x05040100u);
      p01 = __builtin_amdgcn_perm(u1, u0, 0x07030703u);
      p23 = __builtin_amdgcn_perm(u3, u2, 0x07030703u);
      W3  = __builtin_amdgcn_perm(p23, p01, 0x05040100u);
      // addr = kgrp<<10 | j<<8 | ((r<<4)^swzs) | wrd<<2 ; bank 2-way = free
      char* base = As + (kgrp << 10) + (((r << 4) ^ swzs)) + (wrd << 2);
      *(unsigned*)(base + 0x000) = W0;
      *(unsigned*)(base + 0x100) = W1;
      *(unsigned*)(base + 0x200) = W2;
      *(unsigned*)(base + 0x300) = W3;
    }
    __syncthreads();

    // ---- consume: MS steps x {4 ds_read + 5 B loads + 14 MFMAs} (R13) ----
    #pragma unroll
    for (int m = 0; m < MS; ++m) {
      const int kq   = 4 * m + kg;
      const int swzr = ((kq >> 1) & 7) << 4;
      const char* abase = As + (kq << 10) + (((l15 << 4) ^ swzr));
      i32x4 a0 = *(const i32x4*)(abase + 0x000);
      i32x4 a1 = *(const i32x4*)(abase + 0x100);
      i32x4 a2 = *(const i32x4*)(abase + 0x200);
      i32x4 a3 = *(const i32x4*)(abase + 0x300);
      i32x4 b0 = *(const i32x4*)(bpp);
      i32x4 b1 = *(const i32x4*)(bpp + 1024);
      i32x4 b2 = *(const i32x4*)(bpp + 2048);
      i32x4 b3 = *(const i32x4*)(bpp + 3072);
      i32x4 b4 = *(const i32x4*)(bpp + 4096);
      bpp += 20480;
      acc3 = __builtin_amdgcn_mfma_i32_16x16x64_i8(a0, b3, acc3, 0, 0, 0);
      acc4 = __builtin_amdgcn_mfma_i32_16x16x64_i8(a0, b4, acc4, 0, 0, 0);
      acc5 = __builtin_amdgcn_mfma_i32_16x16x64_i8(a1, b4, acc5, 0, 0, 0);
      acc6 = __builtin_amdgcn_mfma_i32_16x16x64_i8(a2, b4, acc6, 0, 0, 0);
      acc7 = __builtin_amdgcn_mfma_i32_16x16x64_i8(a3, b4, acc7, 0, 0, 0);
      acc3 = __builtin_amdgcn_mfma_i32_16x16x64_i8(a1, b2, acc3, 0, 0, 0);
      acc4 = __builtin_amdgcn_mfma_i32_16x16x64_i8(a1, b3, acc4, 0, 0, 0);
      acc5 = __builtin_amdgcn_mfma_i32_16x16x64_i8(a2, b3, acc5, 0, 0, 0);
      acc6 = __builtin_amdgcn_mfma_i32_16x16x64_i8(a3, b3, acc6, 0, 0, 0);
      acc3 = __builtin_amdgcn_mfma_i32_16x16x64_i8(a2, b1, acc3, 0, 0, 0);
      acc4 = __builtin_amdgcn_mfma_i32_16x16x64_i8(a2, b2, acc4, 0, 0, 0);
      acc5 = __builtin_amdgcn_mfma_i32_16x16x64_i8(a3, b2, acc5, 0, 0, 0);
      acc3 = __builtin_amdgcn_mfma_i32_16x16x64_i8(a3, b0, acc3, 0, 0, 0);
      acc4 = __builtin_amdgcn_mfma_i32_16x16x64_i8(a3, b1, acc4, 0, 0, 0);
    }
    __syncthreads();
  }

  // ---- f64 combine: wave owns its 16x16 logits (R11-proven) ----
  #pragma unroll
  for (int r = 0; r < 4; ++r) {
    int ex = w * 16 + qcol[r];
    double part = (16777216.0              * (double)acc3[r]
                 + 4294967296.0            * (double)acc4[r]
                 + 1099511627776.0         * (double)acc5[r]
                 + 281474976710656.0       * (double)acc6[r]
                 + 72057594037927936.0     * (double)acc7[r]
                 + 8421504.0 * compRaw[ex]) * 1.6940658945086007e-21;
    Ls[qrow[r] * E + ex] = part;
  }
  __syncthreads();

  // ---- softmax + top-8: selection on f64 logits, weights in f32 ----
  for (int tt2 = 0; tt2 < 4; tt2++) {
    int t = w * 4 + tt2;
    double val = Ls[t * E + lane];

    double mx = val;
    #pragma unroll
    for (int off = 32; off >= 1; off >>= 1)
      mx = fmax(mx, __shfl_xor(mx, off));

    float p = expf((float)(val - mx));
    float S = p;
    #pragma unroll
    for (int off = 32; off >= 1; off >>= 1)
      S += __shfl_xor(S, off);

    double cur = val;
    float myw = 0.f; int myidx = 0;
    float psum = 0.f;
    #pragma unroll
    for (int r = 0; r < TOPK; r++) {
      double v = cur; int ii = lane;
      #pragma unroll
      for (int off = 32; off >= 1; off >>= 1) {
        double ov = __shfl_xor(v, off);
        int    oi = __shfl_xor(ii, off);
        if (ov > v || (ov == v && oi < ii)) { v = ov; ii = oi; }
      }
      float pw = __shfl(p, ii);
      psum += pw;
      if (lane == r) { myw = pw; myidx = ii; }
      if (lane == ii) cur = -INFINITY;
    }
    float denom = psum + 1e-20f * S;
    if (lane < TOPK) {
      size_t gt = (size_t)(t0 + t);
      out[gt * TOPK + lane] = myw / denom;
      out[(size_t)n_tokens * TOPK + gt * TOPK + lane] = (float)myidx;
    }
  }
}

extern "C" void kernel_launch(void* const* d_in, const int* in_sizes, int n_in,
                              void* d_out, int out_size, void* d_ws, size_t ws_size,
                              hipStream_t stream)
{
  const float* X  = (const float*)d_in[0];
  const float* Wg = (const float*)d_in[1];
  float* out = (float*)d_out;
  signed char* Wb = (signed char*)d_ws;                 // 1.25 MB limb planes
  double* compRaw = (double*)((char*)d_ws + 1310720);   // 512 B raw comp sums
  int n_tokens = in_sizes[0] / H;                        // 16384

  hipMemsetAsync(compRaw, 0, E * sizeof(double), stream);
  prep_w<<<64, 256, 0, stream>>>(Wg, Wb, compRaw);
  moe_gate_i8<<<n_tokens / TILE_T, 256, 0, stream>>>(X, Wb, compRaw, out, n_tokens);
}

// Round 26
// 117.523 us; speedup vs baseline: 1.5678x; 1.0334x over previous
//
#include <hip/hip_runtime.h>
#include <math.h>

typedef float  f32x4  __attribute__((ext_vector_type(4)));
typedef int    i32x4  __attribute__((ext_vector_type(4)));

#define H      4096
#define E      64
#define TOPK   8
#define TILE_T 16
#define CK     256     // k per staged chunk
#define MS     4       // 64-k MFMA steps per chunk
#define NCH    16      // chunks

// W -> 5 balanced i8 limbs of round(w*2^41) (R11-proven layout) + comp via
// IN-BLOCK reduce: block b covers n in [256b,256b+256) -> e == blockIdx.x is
// block-uniform, so csum reduces across the block (exact integer f64 adds)
// and stores compRaw[e] with a plain store. R26: drops the memset launch
// and the atomics (R25's fusion kept both).
__global__ __launch_bounds__(256)
void prep_w(const float* __restrict__ Wg, signed char* __restrict__ Wb,
            double* __restrict__ compRaw)
{
  __shared__ double cs[4];
  int n = blockIdx.x * 256 + threadIdx.x;   // 16384 = e(64) x m(64) x kgrp(4)
  int kgrp = n & 3, m = (n >> 2) & 63, e = n >> 8;   // e == blockIdx.x
  const float* wp = Wg + e * 4096 + m * 64 + kgrp * 16;
  signed char lb[5][16];
  double csum = 0.0;
  #pragma unroll
  for (int s = 0; s < 16; ++s) {
    long long v = (long long)rint((double)wp[s] * 2199023255552.0); // 2^41
    csum += (double)v;
    #pragma unroll
    for (int j = 0; j < 4; ++j) {
      signed char b = (signed char)(v & 0xff);
      lb[j][s] = b;
      v = (v - b) >> 8;
    }
    lb[4][s] = (signed char)v;
  }
  int lanei = (kgrp << 4) | (e & 15);
  int eq = e >> 4;
  #pragma unroll
  for (int j = 0; j < 5; ++j) {
    i32x4 d;
    #pragma unroll
    for (int r = 0; r < 4; ++r)
      d[r] = (lb[j][4*r] & 0xFF) | ((lb[j][4*r+1] & 0xFF) << 8)
           | ((lb[j][4*r+2] & 0xFF) << 16) | ((lb[j][4*r+3] & 0xFF) << 24);
    *(i32x4*)(Wb + (((size_t)(m * 4 + eq) * 5 + j) << 10) + lanei * 16) = d;
  }
  // exact block reduce: wave sums (integer-valued f64) -> LDS -> lane 0
  #pragma unroll
  for (int off = 32; off >= 1; off >>= 1)
    csum += __shfl_xor(csum, off);
  if ((threadIdx.x & 63) == 0) cs[threadIdx.x >> 6] = csum;
  __syncthreads();
  if (threadIdx.x == 0)
    compRaw[e] = cs[0] + cs[1] + cs[2] + cs[3];
}

// R26 main = R20 VERBATIM (best: 118.8us wall; 10 structural variants all
// regressed/nulled against it); compT = 8421504.0*compRaw at use (R25-proven).
__global__ __launch_bounds__(256)
void moe_gate_i8(const float* __restrict__ X, const signed char* __restrict__ Wb,
                 const double* __restrict__ compRaw, float* __restrict__ out,
                 int n_tokens)
{
  __shared__ char As[16384];     // [kgrp16][limb4][tok16]x16B, swizzled
  double* Ls = (double*)As;      // aliased epilogue logits [16][64]

  const int tid  = threadIdx.x;
  const int lane = tid & 63;
  const int w    = tid >> 6;     // expert quad 0..3 (also stager of 4 rows)
  const int t0   = blockIdx.x * TILE_T;
  const int l15  = lane & 15;
  const int kg   = lane >> 4;

  // ---- probe (lane,reg)->(row,col) readout (R11-proven) ----
  i32x4 z = {0, 0, 0, 0};
  int lab = l15 * 0x01010101;
  i32x4 onev = {0x01010101, 0x01010101, 0x01010101, 0x01010101};
  i32x4 labv = {lab, lab, lab, lab};
  i32x4 pr = __builtin_amdgcn_mfma_i32_16x16x64_i8(labv, onev, z, 0, 0, 0);
  i32x4 pc = __builtin_amdgcn_mfma_i32_16x16x64_i8(onev, labv, z, 0, 0, 0);
  int qrow[4], qcol[4];
  #pragma unroll
  for (int r = 0; r < 4; ++r) { qrow[r] = pr[r] >> 6; qcol[r] = pc[r] >> 6; }

  i32x4 acc3 = z, acc4 = z, acc5 = z, acc6 = z, acc7 = z;

  // staging (R20-proven): wave w stages rows w*4..w*4+3, one coalesced
  // f32x4 per row; per-lane CONV; b32 scatter at 2 lanes/bank (free)
  const int kgrp = lane >> 2;                  // 0..15
  const int wrd  = lane & 3;
  const int swzs = ((lane >> 3) & 7) << 4;     // ((kgrp>>1)&7)<<4
  const float* xbase = X + (size_t)t0 * H + lane * 4;

  const signed char* bpp = Wb + w * 5120 + lane * 16;

  for (int c = 0; c < NCH; ++c) {
    // ---- coalesced load: one f32x4 per row (4 rows per wave) ----
    f32x4 xr[4];
    #pragma unroll
    for (int q = 0; q < 4; ++q)
      xr[q] = *(const f32x4*)(xbase + (size_t)(w * 4 + q) * H + c * CK);

    // ---- per-lane CONV (once per block) + swizzled b32 scatter ----
    #pragma unroll
    for (int q = 0; q < 4; ++q) {
      const int r = w * 4 + q;
      unsigned u0 = ((unsigned)(int)(xr[q][0] * 268435456.0f)) ^ 0x00808080u;
      unsigned u1 = ((unsigned)(int)(xr[q][1] * 268435456.0f)) ^ 0x00808080u;
      unsigned u2 = ((unsigned)(int)(xr[q][2] * 268435456.0f)) ^ 0x00808080u;
      unsigned u3 = ((unsigned)(int)(xr[q][3] * 268435456.0f)) ^ 0x00808080u;
      unsigned p01, p23, W0, W1, W2, W3;
      p01 = __builtin_amdgcn_perm(u1, u0, 0x04000400u);
      p23 = __builtin_amdgcn_perm(u3, u2, 0x04000400u);
      W0  = __builtin_amdgcn_perm(p23, p01, 0x05040100u);
      p01 = __builtin_amdgcn_perm(u1, u0, 0x05010501u);
      p23 = __builtin_amdgcn_perm(u3, u2, 0x05010501u);
      W1  = __builtin_amdgcn_perm(p23, p01, 0x05040100u);
      p01 = __builtin_amdgcn_perm(u1, u0, 0x06020602u);
      p23 = __builtin_amdgcn_perm(u3, u2, 0x06020602u);
      W2  = __builtin_amdgcn_perm(p23, p01, 0x05040100u);
      p01 = __builtin_amdgcn_perm(u1, u0, 0x07030703u);
      p23 = __builtin_amdgcn_perm(u3, u2, 0x07030703u);
      W3  = __builtin_amdgcn_perm(p23, p01, 0x05040100u);
      // addr = kgrp<<10 | j<<8 | ((r<<4)^swzs) | wrd<<2 ; bank 2-way = free
      char* base = As + (kgrp << 10) + (((r << 4) ^ swzs)) + (wrd << 2);
      *(unsigned*)(base + 0x000) = W0;
      *(unsigned*)(base + 0x100) = W1;
      *(unsigned*)(base + 0x200) = W2;
      *(unsigned*)(base + 0x300) = W3;
    }
    __syncthreads();

    // ---- consume: MS steps x {4 ds_read + 5 B loads + 14 MFMAs} (R13) ----
    #pragma unroll
    for (int m = 0; m < MS; ++m) {
      const int kq   = 4 * m + kg;
      const int swzr = ((kq >> 1) & 7) << 4;
      const char* abase = As + (kq << 10) + (((l15 << 4) ^ swzr));
      i32x4 a0 = *(const i32x4*)(abase + 0x000);
      i32x4 a1 = *(const i32x4*)(abase + 0x100);
      i32x4 a2 = *(const i32x4*)(abase + 0x200);
      i32x4 a3 = *(const i32x4*)(abase + 0x300);
      i32x4 b0 = *(const i32x4*)(bpp);
      i32x4 b1 = *(const i32x4*)(bpp + 1024);
      i32x4 b2 = *(const i32x4*)(bpp + 2048);
      i32x4 b3 = *(const i32x4*)(bpp + 3072);
      i32x4 b4 = *(const i32x4*)(bpp + 4096);
      bpp += 20480;
      acc3 = __builtin_amdgcn_mfma_i32_16x16x64_i8(a0, b3, acc3, 0, 0, 0);
      acc4 = __builtin_amdgcn_mfma_i32_16x16x64_i8(a0, b4, acc4, 0, 0, 0);
      acc5 = __builtin_amdgcn_mfma_i32_16x16x64_i8(a1, b4, acc5, 0, 0, 0);
      acc6 = __builtin_amdgcn_mfma_i32_16x16x64_i8(a2, b4, acc6, 0, 0, 0);
      acc7 = __builtin_amdgcn_mfma_i32_16x16x64_i8(a3, b4, acc7, 0, 0, 0);
      acc3 = __builtin_amdgcn_mfma_i32_16x16x64_i8(a1, b2, acc3, 0, 0, 0);
      acc4 = __builtin_amdgcn_mfma_i32_16x16x64_i8(a1, b3, acc4, 0, 0, 0);
      acc5 = __builtin_amdgcn_mfma_i32_16x16x64_i8(a2, b3, acc5, 0, 0, 0);
      acc6 = __builtin_amdgcn_mfma_i32_16x16x64_i8(a3, b3, acc6, 0, 0, 0);
      acc3 = __builtin_amdgcn_mfma_i32_16x16x64_i8(a2, b1, acc3, 0, 0, 0);
      acc4 = __builtin_amdgcn_mfma_i32_16x16x64_i8(a2, b2, acc4, 0, 0, 0);
      acc5 = __builtin_amdgcn_mfma_i32_16x16x64_i8(a3, b2, acc5, 0, 0, 0);
      acc3 = __builtin_amdgcn_mfma_i32_16x16x64_i8(a3, b0, acc3, 0, 0, 0);
      acc4 = __builtin_amdgcn_mfma_i32_16x16x64_i8(a3, b1, acc4, 0, 0, 0);
    }
    __syncthreads();
  }

  // ---- f64 combine: wave owns its 16x16 logits (R11-proven) ----
  #pragma unroll
  for (int r = 0; r < 4; ++r) {
    int ex = w * 16 + qcol[r];
    double part = (16777216.0              * (double)acc3[r]
                 + 4294967296.0            * (double)acc4[r]
                 + 1099511627776.0         * (double)acc5[r]
                 + 281474976710656.0       * (double)acc6[r]
                 + 72057594037927936.0     * (double)acc7[r]
                 + 8421504.0 * compRaw[ex]) * 1.6940658945086007e-21;
    Ls[qrow[r] * E + ex] = part;
  }
  __syncthreads();

  // ---- softmax + top-8: selection on f64 logits, weights in f32 ----
  for (int tt2 = 0; tt2 < 4; tt2++) {
    int t = w * 4 + tt2;
    double val = Ls[t * E + lane];

    double mx = val;
    #pragma unroll
    for (int off = 32; off >= 1; off >>= 1)
      mx = fmax(mx, __shfl_xor(mx, off));

    float p = expf((float)(val - mx));
    float S = p;
    #pragma unroll
    for (int off = 32; off >= 1; off >>= 1)
      S += __shfl_xor(S, off);

    double cur = val;
    float myw = 0.f; int myidx = 0;
    float psum = 0.f;
    #pragma unroll
    for (int r = 0; r < TOPK; r++) {
      double v = cur; int ii = lane;
      #pragma unroll
      for (int off = 32; off >= 1; off >>= 1) {
        double ov = __shfl_xor(v, off);
        int    oi = __shfl_xor(ii, off);
        if (ov > v || (ov == v && oi < ii)) { v = ov; ii = oi; }
      }
      float pw = __shfl(p, ii);
      psum += pw;
      if (lane == r) { myw = pw; myidx = ii; }
      if (lane == ii) cur = -INFINITY;
    }
    float denom = psum + 1e-20f * S;
    if (lane < TOPK) {
      size_t gt = (size_t)(t0 + t);
      out[gt * TOPK + lane] = myw / denom;
      out[(size_t)n_tokens * TOPK + gt * TOPK + lane] = (float)myidx;
    }
  }
}

extern "C" void kernel_launch(void* const* d_in, const int* in_sizes, int n_in,
                              void* d_out, int out_size, void* d_ws, size_t ws_size,
                              hipStream_t stream)
{
  const float* X  = (const float*)d_in[0];
  const float* Wg = (const float*)d_in[1];
  float* out = (float*)d_out;
  signed char* Wb = (signed char*)d_ws;                 // 1.25 MB limb planes
  double* compRaw = (double*)((char*)d_ws + 1310720);   // 512 B raw comp sums
  int n_tokens = in_sizes[0] / H;                        // 16384

  prep_w<<<64, 256, 0, stream>>>(Wg, Wb, compRaw);
  moe_gate_i8<<<n_tokens / TILE_T, 256, 0, stream>>>(X, Wb, compRaw, out, n_tokens);
}